// Round 6
// baseline (557.113 us; speedup 1.0000x reference)
//
#include <hip/hip_runtime.h>

typedef __bf16 bf16;
typedef __bf16 bf16x2 __attribute__((ext_vector_type(2)));
typedef __bf16 bf16x4 __attribute__((ext_vector_type(4)));
typedef __bf16 bf16x8 __attribute__((ext_vector_type(8)));
typedef float  f32x4  __attribute__((ext_vector_type(4)));

#define MFMA16(a,b,c) __builtin_amdgcn_mfma_f32_16x16x32_bf16((a),(b),(c),0,0,0)

constexpr int Bn = 8, Sn = 4096, En = 2048, Ln = 64, Hn = 128;
constexpr int Mrows = Bn * Sn; // 32768

__device__ __forceinline__ void load_lds_16(const bf16* g, bf16* l) {
    __builtin_amdgcn_global_load_lds(
        (const __attribute__((address_space(1))) uint32_t*)g,
        (__attribute__((address_space(3))) uint32_t*)l, 16, 0, 0);
}

// ---------------- transpose + fp32->bf16: in[K][N] -> out[N][K] ----------------
__global__ __launch_bounds__(256) void transpose_cvt(const float* __restrict__ in,
                                                     bf16* __restrict__ out,
                                                     int K, int N) {
    int tid = blockIdx.x * 256 + threadIdx.x;
    if (tid >= K * N) return;
    int k = tid / N, n = tid - k * N;
    out[n * K + k] = (bf16)in[tid];
}

// ---------------- fused latent+q GEMM + k/v decompression epilogue ----------------
// C = x @ [w_dkv | w_q]; then k = latent@w_k, v^T = (latent@w_v)^T in the epilogue.
// 512 threads = 8 waves: wave = (mgrp 0..3) x (nhalf 0..1). BM=64, BN=192, BK=64.
__global__ __launch_bounds__(512) void gemm_xw(const float* __restrict__ x,
                                               const bf16* __restrict__ wT,    // [192][2048]
                                               const bf16* __restrict__ wkT,   // [128][64]
                                               const bf16* __restrict__ wvT,   // [128][64]
                                               float* __restrict__ latent_out, // [32768][64] fp32
                                               bf16* __restrict__ q_out,       // [32768][128] bf16
                                               bf16* __restrict__ k_out,       // [32768][128] bf16
                                               bf16* __restrict__ vT_out) {    // [8][128][4096] bf16
    __shared__ __align__(16) bf16 As[64 * 72];   // [row][k], +8 pad (reused as latent tile)
    __shared__ __align__(16) bf16 Bs[192 * 64];  // [n][k] XOR-swizzled, unpadded
    const int lane = threadIdx.x & 63;
    const int wave = threadIdx.x >> 6;           // 0..7
    const int col  = lane & 15, quad = lane >> 4;
    const int mgrp  = wave >> 1;                 // 0..3 : rows mgrp*16..+16
    const int nhalf = wave & 1;                  // 0..1 : nt 0..5 / 6..11
    const int mblock = blockIdx.x * 64;

    f32x4 acc[6];
#pragma unroll
    for (int t = 0; t < 6; ++t) acc[t] = (f32x4){0.f, 0.f, 0.f, 0.f};

    const int bsub = lane >> 3;             // 0..7 sub-row for B staging
    const int bkg0 = lane & 7;
    const int akc  = threadIdx.x & 15;      // 0..15 f32x4 column
    const int arow0 = threadIdx.x >> 4;     // 0..31

    for (int step = 0; step < 32; ++step) {
        __syncthreads();
        // --- B staging: 3 x global_load_lds per wave (8 rows x 128B each) ---
#pragma unroll
        for (int j = 0; j < 3; ++j) {
            int nr0 = wave * 24 + j * 8;
            int n = nr0 + bsub;
            int kgrp = bkg0 ^ bsub;            // XOR swizzle via global addr perm
            const bf16* g = wT + (size_t)n * En + step * 64 + kgrp * 8;
            load_lds_16(g, &Bs[nr0 * 64]);
        }
        // --- A staging: fp32 -> bf16 -> LDS, fully coalesced 16B/lane ---
#pragma unroll
        for (int p = 0; p < 2; ++p) {
            int row = p * 32 + arow0;
            f32x4 v = *(const f32x4*)(x + (size_t)(mblock + row) * En + step * 64 + akc * 4);
            bf16x4 c;
#pragma unroll
            for (int j = 0; j < 4; ++j) c[j] = (bf16)v[j];
            *(bf16x4*)(&As[row * 72 + akc * 4]) = c;
        }
        __syncthreads();
        // --- compute: 2 k-substeps x 6 n-tiles per wave ---
#pragma unroll
        for (int ks2 = 0; ks2 < 2; ++ks2) {
            bf16x8 a = *(const bf16x8*)(&As[(mgrp * 16 + col) * 72 + ks2 * 32 + quad * 8]);
#pragma unroll
            for (int t = 0; t < 6; ++t) {
                int n = nhalf * 96 + t * 16 + col;
                int sg = (ks2 * 4 + quad) ^ (col & 7);
                bf16x8 b = *(const bf16x8*)(&Bs[n * 64 + sg * 8]);
                acc[t] = MFMA16(a, b, acc[t]);
            }
        }
    }
    // ---- epilogue part 1: latent tile -> LDS (bf16), q/latent -> global ----
    __syncthreads();   // drain last compute's As reads before reuse
    if (nhalf == 0) {
#pragma unroll
        for (int t = 0; t < 4; ++t)
#pragma unroll
            for (int r = 0; r < 4; ++r)
                As[(mgrp * 16 + quad * 4 + r) * 72 + t * 16 + col] = (bf16)acc[t][r];
    }
#pragma unroll
    for (int t = 0; t < 6; ++t) {
        int gnt = nhalf * 6 + t;
#pragma unroll
        for (int r = 0; r < 4; ++r) {
            int row = mblock + mgrp * 16 + quad * 4 + r;
            if (gnt < 4) latent_out[(size_t)row * Ln + gnt * 16 + col] = acc[t][r];
            else         q_out[(size_t)row * Hn + (gnt - 4) * 16 + col] = (bf16)acc[t][r];
        }
    }
    __syncthreads();   // latent tile visible to all waves
    // ---- epilogue part 2: k/v decompression GEMM (K-dim = 64) ----
    // nhalf==0 waves -> k tile rows, nhalf==1 waves -> v tile rows (written transposed)
    const bf16* w2 = (nhalf == 0) ? wkT : wvT;
    f32x4 kv[8];
#pragma unroll
    for (int nt = 0; nt < 8; ++nt) kv[nt] = (f32x4){0.f, 0.f, 0.f, 0.f};
#pragma unroll
    for (int ks = 0; ks < 2; ++ks) {
        bf16x8 a = *(const bf16x8*)(&As[(mgrp * 16 + col) * 72 + ks * 32 + quad * 8]);
#pragma unroll
        for (int nt = 0; nt < 8; ++nt) {
            bf16x8 b = *(const bf16x8*)(w2 + (nt * 16 + col) * Ln + ks * 32 + quad * 8);
            kv[nt] = MFMA16(a, b, kv[nt]);
        }
    }
    if (nhalf == 0) {
#pragma unroll
        for (int nt = 0; nt < 8; ++nt)
#pragma unroll
            for (int r = 0; r < 4; ++r) {
                int row = mblock + mgrp * 16 + quad * 4 + r;
                k_out[(size_t)row * Hn + nt * 16 + col] = (bf16)kv[nt][r];
            }
    } else {
        int bb = mblock >> 12;
        int sbase = (mblock & 4095) + mgrp * 16 + quad * 4;
#pragma unroll
        for (int nt = 0; nt < 8; ++nt) {
            bf16x4 pv;
#pragma unroll
            for (int r = 0; r < 4; ++r) pv[r] = (bf16)kv[nt][r];
            *(bf16x4*)(vT_out + ((size_t)bb * Hn + nt * 16 + col) * Sn + sbase) = pv;
        }
    }
}

// ---------------- flash attention, causal, BQ=64 BK=64 D=128 ----------------
// 1D grid, globally work-descending: rank -> qtile = 63 - rank/8, bb = rank%8
// 2 waves x 32 q-rows each (two 16-q fragment groups A/B): every K/V fragment
// read from LDS feeds TWO MFMAs -> LDS read traffic per unit work halves.
// K/V double-buffered; DMA prefetch with counted vmcnt(16) across raw s_barrier.
__global__ __launch_bounds__(128, 1) void mla_attn(const bf16* __restrict__ qg,
                                                   const bf16* __restrict__ kg,
                                                   const bf16* __restrict__ vtg,
                                                   float* __restrict__ outg) {
    __shared__ __align__(16) bf16 Ks[2][64 * 128];   // [key][d] XOR-swizzled (DMA)
    __shared__ __align__(16) bf16 VtS[2][128 * 64];  // [d][key] XOR-swizzled (DMA)
    __shared__ __align__(16) bf16 Pb[2][2][16][72];  // [wave][grp] P [q][key], XOR cols
    const int lane = threadIdx.x & 63;
    const int wave = threadIdx.x >> 6;               // 0..1
    const int col  = lane & 15, quad = lane >> 4;
    const int rank  = blockIdx.x;
    const int qtile = 63 - (rank >> 3);
    const int bb    = rank & 7;
    const int qbase = qtile * 64;
    const bf16* kb  = kg  + (size_t)bb * Sn * Hn;
    const bf16* vbT = vtg + (size_t)bb * Sn * Hn;   // [128][4096]

    bf16x8 qfA[4], qfB[4];
    {
        const bf16* qr = qg + ((size_t)bb * Sn + qbase + wave * 32 + col) * Hn;
#pragma unroll
        for (int ks = 0; ks < 4; ++ks) {
            qfA[ks] = *(const bf16x8*)(qr + ks * 32 + quad * 8);
            qfB[ks] = *(const bf16x8*)(qr + 16 * Hn + ks * 32 + quad * 8);
        }
    }
    f32x4 oA[8], oB[8];
#pragma unroll
    for (int t = 0; t < 8; ++t) {
        oA[t] = (f32x4){0.f, 0.f, 0.f, 0.f};
        oB[t] = (f32x4){0.f, 0.f, 0.f, 0.f};
    }
    float mA = -3.0e38f, mB = -3.0e38f, lA = 0.f, lB = 0.f;
    const float scale = 0.08838834764831845f; // 1/sqrt(128)
    const int qrA = wave * 32 + col;          // local q row of group A (0..63)
    const int qrB = qrA + 16;

    // stage tile kt_ into buffer buf: 16 DMA instrs per wave (8 K + 8 V^T)
    auto stage = [&](int buf, int kt_) {
#pragma unroll
        for (int ii = 0; ii < 8; ++ii) {
            int i = wave * 8 + ii;               // 0..15
            int key = 4 * i + (lane >> 4);
            int p = lane & 15;
            int g = (p & 8) | ((p & 7) ^ (key & 7));  // swizzle on global side
            load_lds_16(kb + (size_t)(kt_ * 64 + key) * Hn + g * 8, &Ks[buf][i * 512]);
        }
#pragma unroll
        for (int ii = 0; ii < 8; ++ii) {
            int i = wave * 8 + ii;               // 0..15 -> d rows i*8..+8
            int r = i * 8 + (lane >> 3);         // d 0..127
            int cs = (lane & 7) ^ (r & 7);       // source chunk (involution)
            load_lds_16(vbT + (size_t)r * Sn + kt_ * 64 + cs * 8, &VtS[buf][i * 512]);
        }
    };

    stage(0, 0);
    for (int kt = 0; kt <= qtile; ++kt) {
        const int cur = kt & 1;
        if (kt < qtile) {
            stage(cur ^ 1, kt + 1);              // prefetch next tile (16 loads in flight)
            asm volatile("s_waitcnt vmcnt(16)" ::: "memory");  // current tile landed
        } else {
            asm volatile("s_waitcnt vmcnt(0)" ::: "memory");
        }
        __builtin_amdgcn_s_barrier();            // all waves' DMA for tile kt landed
        __builtin_amdgcn_sched_barrier(0);
        const bf16* KsC = Ks[cur];
        const bf16* VtC = VtS[cur];

        // --- S^T = K Q^T for both q-groups; each kfr read feeds 2 MFMAs ---
        f32x4 saA[4], saB[4];
#pragma unroll
        for (int nt = 0; nt < 4; ++nt) {
            saA[nt] = (f32x4){0.f, 0.f, 0.f, 0.f};
            saB[nt] = (f32x4){0.f, 0.f, 0.f, 0.f};
#pragma unroll
            for (int ks = 0; ks < 4; ++ks) {
                int key = nt * 16 + col;
                int g = ks * 4 + quad;
                int pos = (g & 8) | ((g & 7) ^ (col & 7));
                bf16x8 kfr = *(const bf16x8*)(KsC + key * 128 + pos * 8);
                saA[nt] = MFMA16(kfr, qfA[ks], saA[nt]);   // D[key][qA]
                saB[nt] = MFMA16(kfr, qfB[ks], saB[nt]);   // D[key][qB]
            }
        }
        // lane holds S[key_local = nt*16 + quad*4 + r][q = qrA / qrB]
        float pA[4][4], pB[4][4];
        if (kt == qtile) {
#pragma unroll
            for (int nt = 0; nt < 4; ++nt)
#pragma unroll
                for (int r = 0; r < 4; ++r) {
                    int key = nt * 16 + quad * 4 + r;
                    float sa_ = saA[nt][r] * scale;
                    float sb_ = saB[nt][r] * scale;
                    if (key > qrA) sa_ = -1.0e30f;
                    if (key > qrB) sb_ = -1.0e30f;
                    pA[nt][r] = sa_;
                    pB[nt][r] = sb_;
                }
        } else {
#pragma unroll
            for (int nt = 0; nt < 4; ++nt)
#pragma unroll
                for (int r = 0; r < 4; ++r) {
                    pA[nt][r] = saA[nt][r] * scale;
                    pB[nt][r] = saB[nt][r] * scale;
                }
        }
        // --- online softmax (in-lane 16-max + 2 shfl), duplicated per group ---
        float mtA = pA[0][0], mtB = pB[0][0];
#pragma unroll
        for (int nt = 0; nt < 4; ++nt)
#pragma unroll
            for (int r = 0; r < 4; ++r) {
                mtA = fmaxf(mtA, pA[nt][r]);
                mtB = fmaxf(mtB, pB[nt][r]);
            }
        mtA = fmaxf(mtA, __shfl_xor(mtA, 16, 64));
        mtA = fmaxf(mtA, __shfl_xor(mtA, 32, 64));
        mtB = fmaxf(mtB, __shfl_xor(mtB, 16, 64));
        mtB = fmaxf(mtB, __shfl_xor(mtB, 32, 64));
        float mnA = fmaxf(mA, mtA), mnB = fmaxf(mB, mtB);
        float alphaA = __expf(mA - mnA), alphaB = __expf(mB - mnB);
        mA = mnA; mB = mnB;
        float rsA = 0.f, rsB = 0.f;
#pragma unroll
        for (int nt = 0; nt < 4; ++nt)
#pragma unroll
            for (int r = 0; r < 4; ++r) {
                float a = __expf(pA[nt][r] - mnA);
                float b = __expf(pB[nt][r] - mnB);
                pA[nt][r] = a; pB[nt][r] = b;
                rsA += a; rsB += b;
            }
        rsA += __shfl_xor(rsA, 16, 64);
        rsA += __shfl_xor(rsA, 32, 64);
        rsB += __shfl_xor(rsB, 16, 64);
        rsB += __shfl_xor(rsB, 32, 64);
        lA = lA * alphaA + rsA;
        lB = lB * alphaB + rsB;
        // --- broadcast alpha to PV accumulator layout (q' = quad*4+r) ---
        float alA[4], alB[4];
#pragma unroll
        for (int r = 0; r < 4; ++r) {
            alA[r] = __shfl(alphaA, quad * 4 + r, 64);
            alB[r] = __shfl(alphaB, quad * 4 + r, 64);
        }
#pragma unroll
        for (int t = 0; t < 8; ++t)
#pragma unroll
            for (int r = 0; r < 4; ++r) {
                oA[t][r] *= alA[r];
                oB[t][r] *= alB[r];
            }
        // --- P -> LDS: 4+4 x ds_write_b64 (wave-private: no barrier needed) ---
#pragma unroll
        for (int nt = 0; nt < 4; ++nt) {
            bf16x4 pva, pvb;
#pragma unroll
            for (int r = 0; r < 4; ++r) { pva[r] = (bf16)pA[nt][r]; pvb[r] = (bf16)pB[nt][r]; }
            int cpos = ((nt ^ (col >> 2)) & 3) * 16 + quad * 4;
            *(bf16x4*)(&Pb[wave][0][col][cpos]) = pva;
            *(bf16x4*)(&Pb[wave][1][col][cpos]) = pvb;
        }
        // --- O += P V; each bv read feeds 2 MFMAs ---
#pragma unroll
        for (int ks = 0; ks < 2; ++ks) {
            int pos = (ks * 32 + quad * 8) ^ ((col >> 2) * 16);
            bf16x8 paA = *(const bf16x8*)(&Pb[wave][0][col][pos]);
            bf16x8 paB = *(const bf16x8*)(&Pb[wave][1][col][pos]);
#pragma unroll
            for (int nt = 0; nt < 8; ++nt) {
                int row = nt * 16 + col;                   // d
                int g = (ks * 4 + quad) ^ (row & 7);       // swizzled 16B chunk
                bf16x8 bv = *(const bf16x8*)(VtC + row * 64 + g * 8);
                oA[nt] = MFMA16(paA, bv, oA[nt]);
                oB[nt] = MFMA16(paB, bv, oB[nt]);
            }
        }
        __builtin_amdgcn_sched_barrier(0);
        __builtin_amdgcn_s_barrier();   // all reads of buf[cur^1]'s predecessor done
    }
    // --- final: bring l into PV layout (q' = quad*4+r), normalize, store ---
    float lrA[4], lrB[4];
#pragma unroll
    for (int r = 0; r < 4; ++r) {
        lrA[r] = __shfl(lA, quad * 4 + r, 64);
        lrB[r] = __shfl(lB, quad * 4 + r, 64);
    }
#pragma unroll
    for (int r = 0; r < 4; ++r) {
        float invA = 1.0f / lrA[r], invB = 1.0f / lrB[r];
        int rowA = qbase + wave * 32 + quad * 4 + r;
        float* oraw = outg + ((size_t)bb * Sn + rowA) * Hn;
#pragma unroll
        for (int t = 0; t < 8; ++t) {
            oraw[t * 16 + col] = oA[t][r] * invA;
            oraw[16 * Hn + t * 16 + col] = oB[t][r] * invB;
        }
    }
}

extern "C" void kernel_launch(void* const* d_in, const int* in_sizes, int n_in,
                              void* d_out, int out_size, void* d_ws, size_t ws_size,
                              hipStream_t stream) {
    const float* x     = (const float*)d_in[0];
    const float* w_dkv = (const float*)d_in[1];
    const float* w_k   = (const float*)d_in[2];
    const float* w_v   = (const float*)d_in[3];
    const float* w_q   = (const float*)d_in[4];

    float* out        = (float*)d_out;                   // [8,4096,128] fp32
    float* latent_out = out + (size_t)Mrows * Hn;        // [8,4096,64]  fp32

    char* ws = (char*)d_ws;
    bf16* q_ws = (bf16*)(ws);                             // 8 MiB
    bf16* k_ws = (bf16*)(ws + (size_t)8  * 1024 * 1024);  // 8 MiB
    bf16* v_ws = (bf16*)(ws + (size_t)16 * 1024 * 1024);  // 8 MiB, V^T [8][128][4096]
    bf16* wT   = (bf16*)(ws + (size_t)24 * 1024 * 1024);  // [192][2048] bf16, 768 KiB
    bf16* wkT  = (bf16*)(ws + (size_t)24 * 1024 * 1024 + 768 * 1024);  // [128][64], 16 KiB
    bf16* wvT  = (bf16*)(ws + (size_t)24 * 1024 * 1024 + 784 * 1024);  // [128][64], 16 KiB

    transpose_cvt<<<(En * Ln + 255) / 256, 256, 0, stream>>>(w_dkv, wT, En, Ln);
    transpose_cvt<<<(En * Hn + 255) / 256, 256, 0, stream>>>(w_q, wT + (size_t)64 * En, En, Hn);
    transpose_cvt<<<(Ln * Hn + 255) / 256, 256, 0, stream>>>(w_k, wkT, Ln, Hn);
    transpose_cvt<<<(Ln * Hn + 255) / 256, 256, 0, stream>>>(w_v, wvT, Ln, Hn);
    gemm_xw<<<Mrows / 64, 512, 0, stream>>>(x, wT, wkT, wvT, latent_out, q_ws, k_ws, v_ws);
    mla_attn<<<Sn / 64 * Bn, 128, 0, stream>>>(q_ws, k_ws, v_ws, out);
}